// Round 17
// baseline (3094.232 us; speedup 1.0000x reference)
//
#include <hip/hip_runtime.h>
#include <hip/hip_fp16.h>
#include <math.h>

#define B_ 64
#define N_ 512
#define H_ 32
#define E_ 4
#define NSTEPS 5
#define KTOT 2048       // N_*E_

typedef _Float16 half8 __attribute__((ext_vector_type(8)));
typedef float   f32x4 __attribute__((ext_vector_type(4)));

// async global->LDS, 16B per lane; LDS dest = wave-uniform base + lane*16
__device__ __forceinline__ void gld16(const void* g, void* l) {
    __builtin_amdgcn_global_load_lds(
        (const __attribute__((address_space(1))) void*)g,
        (__attribute__((address_space(3))) void*)l, 16, 0, 0);
}

// ---------------------------------------------------------------- fused s+einsum
// BOTH DIRS PER BLOCK: block = (nblk, b), 64 chunks cc (dir = cc>>5), pipeline
// carried across the dir boundary (round-10-verified pattern). Grid = 512 =
// exactly 2 blocks/CU -> single residency round, no tail, no mid-step ramp.
// rev alternates traversal direction per step (round-15 L3 mechanism).
// Per chunk: e = (cc>>3)&3, n' = (cc&7)*64..+63.
//   - m-chunk + h-chunk staged via gld16 (6 linear loads/wave)  [vmcnt only]
//   - VALU phase computes B_c = s(n',he) hi/lo into LDS (k_s's exact math)
//   - PUBLISH: s_waitcnt lgkmcnt(0) BEFORE s_barrier (round-13 lesson)
//   - B double-buffered; MFMA phase = round-9 body, bit-identical k-order
#define ABUF 16384      // A: 64 rows x 256B
#define HBUF 8192       // h: 64 rows x 128B
#define BBUF 8192       // B: 2 planes x 32 rows x 128B
__global__ __launch_bounds__(256) void k_es(const float* __restrict__ m,
                                            const float* __restrict__ hsrc,
                                            const float* __restrict__ W_in,
                                            const float* __restrict__ b_in,
                                            const float* __restrict__ W_out,
                                            const float* __restrict__ b_out,
                                            float* __restrict__ a_in,
                                            float* __restrict__ a_out,
                                            int rev) {
    __shared__ __align__(16) char lds[2 * ABUF + 2 * HBUF + 2 * BBUF]; // 64 KB
    int flat = blockIdx.x + (blockIdx.y << 3);        // 0..511
    if (rev) flat = 511 - flat;
    int nblk = flat & 7;
    int b    = flat >> 3;
    int n0   = nblk * 64;
    int tid  = threadIdx.x;
    int w    = tid >> 6;
    int lane = tid & 63;
    int l15  = lane & 15;
    int quad = lane >> 4;
    int hu   = __builtin_amdgcn_readfirstlane(tid >> 6);  // wave-uniform w

    const char* mRow = (const char*)(m + ((size_t)(b * N_ + n0)) * (2 * KTOT));
    const char* hB = (const char*)(hsrc + (size_t)b * N_ * H_);
    const float* Wfd[2] = { W_in, W_out };
    const float* bfd[2] = { b_in, b_out };

    // stage chunk cc: m (4 gld16) + h rows (cc&7)*64.. (2 gld16), 6 loads/wave
    auto STAGE = [&](int cc, int buf) {
        int dir_s = cc >> 5, c = cc & 31;
        char* dA = lds + buf * ABUF;
        char* dH = lds + 2 * ABUF + buf * HBUF;
        const char* mD = mRow + dir_s * (KTOT * 4);
#pragma unroll
        for (int i = 0; i < 4; i++) {                 // A: 4 rows per instr
            int r = (w << 4) + i * 4 + (lane >> 4);
            const char* g = mD + (size_t)r * (2 * KTOT * 4) + c * 256
                            + (((lane & 15) * 16) ^ ((r & 7) << 4));
            gld16(g, dA + ((w << 4) + i * 4) * 256);
        }
        int hrow0 = (cc & 7) * 64;
#pragma unroll
        for (int i = 0; i < 2; i++) {                 // h: 8 rows per instr
            int rl = lane >> 3, pp = lane & 7;
            const char* g = hB + (size_t)(hrow0 + w * 16 + i * 8 + rl) * 128
                            + ((pp ^ (rl & 7)) * 16);
            gld16(g, dH + w * 2048 + i * 1024);
        }
    };

    f32x4 acc0 = {0.f,0.f,0.f,0.f}, acc1 = {0.f,0.f,0.f,0.f};

    int rowA  = (w << 4) + l15;
    int swzA  = (rowA & 7) << 4;
    int swzB0 = (l15 & 7) << 4;       // rows l15 and l15+16 share row&7

    STAGE(0, 0);

    for (int cc = 0; cc < 64; cc++) {
        int buf = cc & 1;
        if (cc < 63) STAGE(cc + 1, buf ^ 1);
        if (cc < 63) asm volatile("s_waitcnt vmcnt(6)" ::: "memory");
        else         asm volatile("s_waitcnt vmcnt(0)" ::: "memory");
        __builtin_amdgcn_s_barrier();          // chunk cc (m,h) visible
        __builtin_amdgcn_sched_barrier(0);

        char* Bb = lds + 2 * ABUF + 2 * HBUF + buf * BBUF;
        int dir_s = cc >> 5;

        // ---- VALU: compute B_c (s projection, k_s's exact expression tree)
        {
            const char* hC = lds + 2 * ABUF + buf * HBUF;
            int j = lane;                      // n'-row handled by this thread
            f32x4 hv[8];
#pragma unroll
            for (int u = 0; u < 8; u++)
                hv[u] = *(const f32x4*)(hC + j * 128 + ((u ^ (j & 7)) * 16));
            int e = (cc >> 3) & 3;
            const float* Wf  = Wfd[dir_s];
            const float* bfp = bfd[dir_s];
#pragma unroll
            for (int i = 0; i < 8; i++) {
                int hr = hu * 8 + i;           // output-H row 0..31 (uniform)
                int he = hr * 4 + e;
                const f32x4* wr = (const f32x4*)(Wf + (size_t)he * H_);
                float acc = bfp[he];
#pragma unroll
                for (int c8 = 0; c8 < 8; c8++) {
                    f32x4 wv = wr[c8];
                    acc += hv[c8][0]*wv[0] + hv[c8][1]*wv[1]
                         + hv[c8][2]*wv[2] + hv[c8][3]*wv[3];
                }
                _Float16 hi = (_Float16)acc;
                _Float16 lo = (_Float16)(acc - (float)hi);
                int byte = hr * 128 + ((j * 2) ^ ((hr & 7) << 4));
                *(_Float16*)(Bb + byte)        = hi;
                *(_Float16*)(Bb + 4096 + byte) = lo;
            }
        }
        // PUBLISH B_c: drain ds_writes BEFORE the barrier
        asm volatile("s_waitcnt lgkmcnt(0)" ::: "memory");
        __builtin_amdgcn_sched_barrier(0);
        __builtin_amdgcn_s_barrier();          // B_c visible to all waves
        __builtin_amdgcn_sched_barrier(0);

        // ---- MFMA chunk cc (round-9 body)
        const char* Ab = lds + buf * ABUF + rowA * 256;
        const char* Bh = Bb;
        const char* Bl = Bb + 4096;
#pragma unroll
        for (int it = 0; it < 2; it++) {
            int kab = it * 128 + quad * 32;          // A byte offset in row
            f32x4 a0 = *(const f32x4*)(Ab + (kab ^ swzA));
            f32x4 a1 = *(const f32x4*)(Ab + ((kab + 16) ^ swzA));

            int kbb = it * 64 + quad * 16;           // B byte offset in row
            int o0 = l15 * 128        + (kbb ^ swzB0);
            int o1 = (l15 + 16) * 128 + (kbb ^ swzB0);
            half8 Bhi0 = *(const half8*)(Bh + o0);
            half8 Bhi1 = *(const half8*)(Bh + o1);
            half8 Blo0 = *(const half8*)(Bl + o0);
            half8 Blo1 = *(const half8*)(Bl + o1);

            half8 Ahi, Alo;
#pragma unroll
            for (int jj = 0; jj < 4; jj++) {
                float v0 = a0[jj], v1 = a1[jj];
                _Float16 h0 = (_Float16)v0, h1 = (_Float16)v1;
                Ahi[jj]     = h0;
                Ahi[jj + 4] = h1;
                Alo[jj]     = (_Float16)(v0 - (float)h0);
                Alo[jj + 4] = (_Float16)(v1 - (float)h1);
            }
            acc0 = __builtin_amdgcn_mfma_f32_16x16x32_f16(Ahi, Bhi0, acc0, 0, 0, 0);
            acc1 = __builtin_amdgcn_mfma_f32_16x16x32_f16(Ahi, Bhi1, acc1, 0, 0, 0);
            acc0 = __builtin_amdgcn_mfma_f32_16x16x32_f16(Ahi, Blo0, acc0, 0, 0, 0);
            acc1 = __builtin_amdgcn_mfma_f32_16x16x32_f16(Ahi, Blo1, acc1, 0, 0, 0);
            acc0 = __builtin_amdgcn_mfma_f32_16x16x32_f16(Alo, Bhi0, acc0, 0, 0, 0);
            acc1 = __builtin_amdgcn_mfma_f32_16x16x32_f16(Alo, Bhi1, acc1, 0, 0, 0);
        }

        if (cc == 31) {                 // dir 0 done: write a_in, reset acc
#pragma unroll
            for (int r = 0; r < 4; r++) {
                size_t rr = (size_t)b * N_ + (n0 + w * 16 + quad * 4 + r);
                a_in[rr * H_ + l15]      = acc0[r];
                a_in[rr * H_ + 16 + l15] = acc1[r];
            }
            acc0 = (f32x4){0.f,0.f,0.f,0.f};
            acc1 = (f32x4){0.f,0.f,0.f,0.f};
        }
        // no trailing barrier needed: A/h rows are self-staged/self-read,
        // and B is double-buffered + publish-barrier-protected.
    }

    // dir 1: write a_out
#pragma unroll
    for (int r = 0; r < 4; r++) {
        size_t rr = (size_t)b * N_ + (n0 + w * 16 + quad * 4 + r);
        a_out[rr * H_ + l15]      = acc0[r];
        a_out[rr * H_ + 16 + l15] = acc1[r];
    }
}

// ---------------------------------------------------------------- GRU gates
// hold comes from hold_src (x at step 0, h afterwards); h written as output
__global__ __launch_bounds__(256) void k_gate(const float* __restrict__ a_in,
                                              const float* __restrict__ a_out,
                                              const float* __restrict__ hold_src,
                                              float* __restrict__ hstate,
                                              const float* __restrict__ Wz,
                                              const float* __restrict__ bz,
                                              const float* __restrict__ Wr,
                                              const float* __restrict__ br,
                                              const float* __restrict__ Wt,
                                              const float* __restrict__ bt) {
    __shared__ float cat[8][96];
    __shared__ float rh[8][32];
    int base = blockIdx.x * 8;     // flattened row b*512+n
    int t = threadIdx.x;

    for (int idx = t; idx < 768; idx += 256) {
        int r = idx / 96, c = idx - r * 96;
        size_t row = (size_t)(base + r);
        float v;
        if (c < 32)      v = a_in [row * 32 + c];
        else if (c < 64) v = a_out[row * 32 + (c - 32)];
        else             v = hold_src[row * 32 + (c - 64)];
        cat[r][c] = v;
    }
    __syncthreads();

    int r = t >> 5, i = t & 31;
    float az = bz[i], ar = br[i];
    const f32x4* wzr = (const f32x4*)(Wz + (size_t)i * 96);
    const f32x4* wrr = (const f32x4*)(Wr + (size_t)i * 96);
    const f32x4* crow = (const f32x4*)cat[r];
#pragma unroll
    for (int kc = 0; kc < 24; kc++) {
        f32x4 cv = crow[kc];
        f32x4 wz = wzr[kc];
        f32x4 wr = wrr[kc];
        az += cv[0]*wz[0] + cv[1]*wz[1] + cv[2]*wz[2] + cv[3]*wz[3];
        ar += cv[0]*wr[0] + cv[1]*wr[1] + cv[2]*wr[2] + cv[3]*wr[3];
    }
    float z  = 1.f / (1.f + __expf(-az));
    float rg = 1.f / (1.f + __expf(-ar));
    float hold = cat[r][64 + i];
    rh[r][i] = rg * hold;
    __syncthreads();

    float at = bt[i];
    const f32x4* wtr = (const f32x4*)(Wt + (size_t)i * 96);
#pragma unroll
    for (int kc = 0; kc < 16; kc++) {     // a_in | a_out part
        f32x4 cv = crow[kc];
        f32x4 wt = wtr[kc];
        at += cv[0]*wt[0] + cv[1]*wt[1] + cv[2]*wt[2] + cv[3]*wt[3];
    }
    const f32x4* rrow = (const f32x4*)rh[r];
#pragma unroll
    for (int kc = 0; kc < 8; kc++) {      // r*h part
        f32x4 cv = rrow[kc];
        f32x4 wt = wtr[16 + kc];
        at += cv[0]*wt[0] + cv[1]*wt[1] + cv[2]*wt[2] + cv[3]*wt[3];
    }
    float hh = tanhf(at);
    hstate[(size_t)(base + r) * 32 + i] = (1.f - z) * hold + z * hh;
}

// ---------------------------------------------------------------- readout
__global__ __launch_bounds__(256) void k_final(const float* __restrict__ hstate,
                                               const float* __restrict__ a,
                                               const float* __restrict__ W1,
                                               const float* __restrict__ b1,
                                               const float* __restrict__ W2,
                                               const float* __restrict__ b2,
                                               float* __restrict__ out) {
    __shared__ float hl[8][32];
    __shared__ float as[8];
    int base = blockIdx.x * 8;
    int t = threadIdx.x;
    {
        int r = t >> 5, c = t & 31;
        hl[r][c] = hstate[(size_t)(base + r) * 32 + c];
        if (t < 8) as[t] = a[base + t];
    }
    __syncthreads();
    int r = t >> 5, j = t & 31;
    float acc = b1[j];
    const float* w1r = W1 + (size_t)j * 33;
#pragma unroll
    for (int i2 = 0; i2 < 32; i2++) acc += hl[r][i2] * w1r[i2];
    acc += as[r] * w1r[32];
    float o = tanhf(acc) * W2[j];
#pragma unroll
    for (int off = 16; off; off >>= 1) o += __shfl_xor(o, off, 32);
    if (j == 0) out[base + r] = o + b2[0];
}

// ---------------------------------------------------------------- launcher
extern "C" void kernel_launch(void* const* d_in, const int* in_sizes, int n_in,
                              void* d_out, int out_size, void* d_ws, size_t ws_size,
                              hipStream_t stream) {
    const float* x     = (const float*)d_in[0];
    const float* a     = (const float*)d_in[1];
    const float* m     = (const float*)d_in[2];
    const float* W_in  = (const float*)d_in[3];
    const float* b_in  = (const float*)d_in[4];
    const float* W_out = (const float*)d_in[5];
    const float* b_out = (const float*)d_in[6];
    const float* Wz    = (const float*)d_in[7];
    const float* bz    = (const float*)d_in[8];
    const float* Wr    = (const float*)d_in[9];
    const float* br    = (const float*)d_in[10];
    const float* Wt    = (const float*)d_in[11];
    const float* bt    = (const float*)d_in[12];
    const float* W1    = (const float*)d_in[13];
    const float* b1    = (const float*)d_in[14];
    const float* W2    = (const float*)d_in[15];
    const float* b2    = (const float*)d_in[16];
    float* out = (float*)d_out;

    char* ws = (char*)d_ws;
    float* h    = (float*)(ws);                        // 4 MB
    float* a_in = (float*)(ws + ((size_t)4 << 20));    // 4 MB
    float* a_out= (float*)(ws + ((size_t)8 << 20));    // 4 MB (12 MB total)

    for (int s = 0; s < NSTEPS; s++) {
        const float* hsrc = (s == 0) ? x : h;
        k_es<<<dim3(8, 64), 256, 0, stream>>>(m, hsrc, W_in, b_in,
                                              W_out, b_out, a_in, a_out,
                                              s & 1);
        k_gate<<<4096, 256, 0, stream>>>(a_in, a_out, hsrc, h,
                                         Wz, bz, Wr, br, Wt, bt);
    }
    k_final<<<4096, 256, 0, stream>>>(h, a, W1, b1, W2, b2, out);
}

// Round 18
// 2150.379 us; speedup vs baseline: 1.4389x; 1.4389x over previous
//
#include <hip/hip_runtime.h>
#include <hip/hip_fp16.h>
#include <math.h>

#define B_ 64
#define N_ 512
#define H_ 32
#define E_ 4
#define NSTEPS 5
#define KTOT 2048       // N_*E_

typedef _Float16 half8 __attribute__((ext_vector_type(8)));
typedef float   f32x4 __attribute__((ext_vector_type(4)));

// async global->LDS, 16B per lane; LDS dest = wave-uniform base + lane*16
__device__ __forceinline__ void gld16(const void* g, void* l) {
    __builtin_amdgcn_global_load_lds(
        (const __attribute__((address_space(1))) void*)g,
        (__attribute__((address_space(3))) void*)l, 16, 0, 0);
}

// ---------------------------------------------------------------- fused s+einsum
// (round-15 verified best: 2143.8 us, absmax 0.0078125)
// block -> tile (nblk, b, dir) via flat id; on odd steps the mapping is
// REVERSED (flat -> 1023-flat) so the step's traversal starts where the
// previous step's ended -> alternating-direction L3 reuse (bit-exact).
// 1024 blocks at 64KB LDS = 2 residency rounds -> staggered phases across
// blocks cover each other's stalls (round-17 lesson: lockstep is slower).
// Per chunk c: e = c>>3, n' = (c&7)*64..+63.
//   - m-chunk + h-chunk staged via gld16 (6 linear loads/wave)  [vmcnt only]
//   - VALU phase computes B_c = s(n',he) hi/lo into LDS (k_s's exact math)
//   - PUBLISH: s_waitcnt lgkmcnt(0) BEFORE s_barrier (round-13 lesson)
//   - B double-buffered; MFMA phase = round-9 body, bit-identical k-order
#define ABUF 16384      // A: 64 rows x 256B
#define HBUF 8192       // h: 64 rows x 128B
#define BBUF 8192       // B: 2 planes x 32 rows x 128B
__global__ __launch_bounds__(256) void k_es(const float* __restrict__ m,
                                            const float* __restrict__ hsrc,
                                            const float* __restrict__ W_in,
                                            const float* __restrict__ b_in,
                                            const float* __restrict__ W_out,
                                            const float* __restrict__ b_out,
                                            float* __restrict__ a_in,
                                            float* __restrict__ a_out,
                                            int rev) {
    __shared__ __align__(16) char lds[2 * ABUF + 2 * HBUF + 2 * BBUF]; // 64 KB
    int flat = blockIdx.x + (blockIdx.y << 3) + (blockIdx.z << 9);  // 0..1023
    if (rev) flat = 1023 - flat;
    int nblk = flat & 7;
    int b    = (flat >> 3) & 63;
    int dir  = flat >> 9;
    int n0   = nblk * 64;
    int tid  = threadIdx.x;
    int w    = tid >> 6;
    int lane = tid & 63;
    int l15  = lane & 15;
    int quad = lane >> 4;
    int hu   = __builtin_amdgcn_readfirstlane(tid >> 6);  // wave-uniform w

    const char* mBase = (const char*)(m + ((size_t)(b * N_ + n0)) * (2 * KTOT)
                                        + (size_t)dir * KTOT);
    const char* hB = (const char*)(hsrc + (size_t)b * N_ * H_);
    const float* Wf  = dir ? W_out : W_in;
    const float* bfp = dir ? b_out : b_in;
    float* aout = dir ? a_out : a_in;

    // stage chunk c: m (4 gld16) + h rows (c&7)*64.. (2 gld16), 6 loads/wave
    auto STAGE = [&](int c, int buf) {
        char* dA = lds + buf * ABUF;
        char* dH = lds + 2 * ABUF + buf * HBUF;
#pragma unroll
        for (int i = 0; i < 4; i++) {                 // A: 4 rows per instr
            int r = (w << 4) + i * 4 + (lane >> 4);
            const char* g = mBase + (size_t)r * (2 * KTOT * 4) + c * 256
                            + (((lane & 15) * 16) ^ ((r & 7) << 4));
            gld16(g, dA + ((w << 4) + i * 4) * 256);
        }
        int hrow0 = (c & 7) * 64;
#pragma unroll
        for (int i = 0; i < 2; i++) {                 // h: 8 rows per instr
            int rl = lane >> 3, pp = lane & 7;
            const char* g = hB + (size_t)(hrow0 + w * 16 + i * 8 + rl) * 128
                            + ((pp ^ (rl & 7)) * 16);
            gld16(g, dH + w * 2048 + i * 1024);
        }
    };

    f32x4 acc0 = {0.f,0.f,0.f,0.f}, acc1 = {0.f,0.f,0.f,0.f};

    int rowA  = (w << 4) + l15;
    int swzA  = (rowA & 7) << 4;
    int swzB0 = (l15 & 7) << 4;       // rows l15 and l15+16 share row&7

    STAGE(0, 0);

    for (int c = 0; c < 32; c++) {
        int buf = c & 1;
        if (c < 31) STAGE(c + 1, buf ^ 1);
        if (c < 31) asm volatile("s_waitcnt vmcnt(6)" ::: "memory");
        else        asm volatile("s_waitcnt vmcnt(0)" ::: "memory");
        __builtin_amdgcn_s_barrier();          // chunk c (m,h) visible
        __builtin_amdgcn_sched_barrier(0);

        char* Bb = lds + 2 * ABUF + 2 * HBUF + buf * BBUF;

        // ---- VALU: compute B_c (s projection, k_s's exact expression tree)
        {
            const char* hC = lds + 2 * ABUF + buf * HBUF;
            int j = lane;                      // n'-row handled by this thread
            f32x4 hv[8];
#pragma unroll
            for (int u = 0; u < 8; u++)
                hv[u] = *(const f32x4*)(hC + j * 128 + ((u ^ (j & 7)) * 16));
            int e = c >> 3;
#pragma unroll
            for (int i = 0; i < 8; i++) {
                int hr = hu * 8 + i;           // output-H row 0..31 (uniform)
                int he = hr * 4 + e;
                const f32x4* wr = (const f32x4*)(Wf + (size_t)he * H_);
                float acc = bfp[he];
#pragma unroll
                for (int c8 = 0; c8 < 8; c8++) {
                    f32x4 wv = wr[c8];
                    acc += hv[c8][0]*wv[0] + hv[c8][1]*wv[1]
                         + hv[c8][2]*wv[2] + hv[c8][3]*wv[3];
                }
                _Float16 hi = (_Float16)acc;
                _Float16 lo = (_Float16)(acc - (float)hi);
                int byte = hr * 128 + ((j * 2) ^ ((hr & 7) << 4));
                *(_Float16*)(Bb + byte)        = hi;
                *(_Float16*)(Bb + 4096 + byte) = lo;
            }
        }
        // PUBLISH B_c: drain ds_writes BEFORE the barrier
        asm volatile("s_waitcnt lgkmcnt(0)" ::: "memory");
        __builtin_amdgcn_sched_barrier(0);
        __builtin_amdgcn_s_barrier();          // B_c visible to all waves
        __builtin_amdgcn_sched_barrier(0);

        // ---- MFMA chunk c (round-9 body)
        const char* Ab = lds + buf * ABUF + rowA * 256;
        const char* Bh = Bb;
        const char* Bl = Bb + 4096;
#pragma unroll
        for (int it = 0; it < 2; it++) {
            int kab = it * 128 + quad * 32;          // A byte offset in row
            f32x4 a0 = *(const f32x4*)(Ab + (kab ^ swzA));
            f32x4 a1 = *(const f32x4*)(Ab + ((kab + 16) ^ swzA));

            int kbb = it * 64 + quad * 16;           // B byte offset in row
            int o0 = l15 * 128        + (kbb ^ swzB0);
            int o1 = (l15 + 16) * 128 + (kbb ^ swzB0);
            half8 Bhi0 = *(const half8*)(Bh + o0);
            half8 Bhi1 = *(const half8*)(Bh + o1);
            half8 Blo0 = *(const half8*)(Bl + o0);
            half8 Blo1 = *(const half8*)(Bl + o1);

            half8 Ahi, Alo;
#pragma unroll
            for (int jj = 0; jj < 4; jj++) {
                float v0 = a0[jj], v1 = a1[jj];
                _Float16 h0 = (_Float16)v0, h1 = (_Float16)v1;
                Ahi[jj]     = h0;
                Ahi[jj + 4] = h1;
                Alo[jj]     = (_Float16)(v0 - (float)h0);
                Alo[jj + 4] = (_Float16)(v1 - (float)h1);
            }
            acc0 = __builtin_amdgcn_mfma_f32_16x16x32_f16(Ahi, Bhi0, acc0, 0, 0, 0);
            acc1 = __builtin_amdgcn_mfma_f32_16x16x32_f16(Ahi, Bhi1, acc1, 0, 0, 0);
            acc0 = __builtin_amdgcn_mfma_f32_16x16x32_f16(Ahi, Blo0, acc0, 0, 0, 0);
            acc1 = __builtin_amdgcn_mfma_f32_16x16x32_f16(Ahi, Blo1, acc1, 0, 0, 0);
            acc0 = __builtin_amdgcn_mfma_f32_16x16x32_f16(Alo, Bhi0, acc0, 0, 0, 0);
            acc1 = __builtin_amdgcn_mfma_f32_16x16x32_f16(Alo, Bhi1, acc1, 0, 0, 0);
        }
        // no trailing barrier needed: A/h rows are self-staged/self-read,
        // and B is double-buffered + publish-barrier-protected.
    }

    // D layout: row = quad*4 + r (within 16-row tile), col = l15 (+16 for acc1)
#pragma unroll
    for (int r = 0; r < 4; r++) {
        size_t rr = (size_t)b * N_ + (n0 + w * 16 + quad * 4 + r);
        aout[rr * H_ + l15]      = acc0[r];
        aout[rr * H_ + 16 + l15] = acc1[r];
    }
}

// ---------------------------------------------------------------- GRU gates
// hold comes from hold_src (x at step 0, h afterwards); h written as output
__global__ __launch_bounds__(256) void k_gate(const float* __restrict__ a_in,
                                              const float* __restrict__ a_out,
                                              const float* __restrict__ hold_src,
                                              float* __restrict__ hstate,
                                              const float* __restrict__ Wz,
                                              const float* __restrict__ bz,
                                              const float* __restrict__ Wr,
                                              const float* __restrict__ br,
                                              const float* __restrict__ Wt,
                                              const float* __restrict__ bt) {
    __shared__ float cat[8][96];
    __shared__ float rh[8][32];
    int base = blockIdx.x * 8;     // flattened row b*512+n
    int t = threadIdx.x;

    for (int idx = t; idx < 768; idx += 256) {
        int r = idx / 96, c = idx - r * 96;
        size_t row = (size_t)(base + r);
        float v;
        if (c < 32)      v = a_in [row * 32 + c];
        else if (c < 64) v = a_out[row * 32 + (c - 32)];
        else             v = hold_src[row * 32 + (c - 64)];
        cat[r][c] = v;
    }
    __syncthreads();

    int r = t >> 5, i = t & 31;
    float az = bz[i], ar = br[i];
    const f32x4* wzr = (const f32x4*)(Wz + (size_t)i * 96);
    const f32x4* wrr = (const f32x4*)(Wr + (size_t)i * 96);
    const f32x4* crow = (const f32x4*)cat[r];
#pragma unroll
    for (int kc = 0; kc < 24; kc++) {
        f32x4 cv = crow[kc];
        f32x4 wz = wzr[kc];
        f32x4 wr = wrr[kc];
        az += cv[0]*wz[0] + cv[1]*wz[1] + cv[2]*wz[2] + cv[3]*wz[3];
        ar += cv[0]*wr[0] + cv[1]*wr[1] + cv[2]*wr[2] + cv[3]*wr[3];
    }
    float z  = 1.f / (1.f + __expf(-az));
    float rg = 1.f / (1.f + __expf(-ar));
    float hold = cat[r][64 + i];
    rh[r][i] = rg * hold;
    __syncthreads();

    float at = bt[i];
    const f32x4* wtr = (const f32x4*)(Wt + (size_t)i * 96);
#pragma unroll
    for (int kc = 0; kc < 16; kc++) {     // a_in | a_out part
        f32x4 cv = crow[kc];
        f32x4 wt = wtr[kc];
        at += cv[0]*wt[0] + cv[1]*wt[1] + cv[2]*wt[2] + cv[3]*wt[3];
    }
    const f32x4* rrow = (const f32x4*)rh[r];
#pragma unroll
    for (int kc = 0; kc < 8; kc++) {      // r*h part
        f32x4 cv = rrow[kc];
        f32x4 wt = wtr[16 + kc];
        at += cv[0]*wt[0] + cv[1]*wt[1] + cv[2]*wt[2] + cv[3]*wt[3];
    }
    float hh = tanhf(at);
    hstate[(size_t)(base + r) * 32 + i] = (1.f - z) * hold + z * hh;
}

// ---------------------------------------------------------------- readout
__global__ __launch_bounds__(256) void k_final(const float* __restrict__ hstate,
                                               const float* __restrict__ a,
                                               const float* __restrict__ W1,
                                               const float* __restrict__ b1,
                                               const float* __restrict__ W2,
                                               const float* __restrict__ b2,
                                               float* __restrict__ out) {
    __shared__ float hl[8][32];
    __shared__ float as[8];
    int base = blockIdx.x * 8;
    int t = threadIdx.x;
    {
        int r = t >> 5, c = t & 31;
        hl[r][c] = hstate[(size_t)(base + r) * 32 + c];
        if (t < 8) as[t] = a[base + t];
    }
    __syncthreads();
    int r = t >> 5, j = t & 31;
    float acc = b1[j];
    const float* w1r = W1 + (size_t)j * 33;
#pragma unroll
    for (int i2 = 0; i2 < 32; i2++) acc += hl[r][i2] * w1r[i2];
    acc += as[r] * w1r[32];
    float o = tanhf(acc) * W2[j];
#pragma unroll
    for (int off = 16; off; off >>= 1) o += __shfl_xor(o, off, 32);
    if (j == 0) out[base + r] = o + b2[0];
}

// ---------------------------------------------------------------- launcher
extern "C" void kernel_launch(void* const* d_in, const int* in_sizes, int n_in,
                              void* d_out, int out_size, void* d_ws, size_t ws_size,
                              hipStream_t stream) {
    const float* x     = (const float*)d_in[0];
    const float* a     = (const float*)d_in[1];
    const float* m     = (const float*)d_in[2];
    const float* W_in  = (const float*)d_in[3];
    const float* b_in  = (const float*)d_in[4];
    const float* W_out = (const float*)d_in[5];
    const float* b_out = (const float*)d_in[6];
    const float* Wz    = (const float*)d_in[7];
    const float* bz    = (const float*)d_in[8];
    const float* Wr    = (const float*)d_in[9];
    const float* br    = (const float*)d_in[10];
    const float* Wt    = (const float*)d_in[11];
    const float* bt    = (const float*)d_in[12];
    const float* W1    = (const float*)d_in[13];
    const float* b1    = (const float*)d_in[14];
    const float* W2    = (const float*)d_in[15];
    const float* b2    = (const float*)d_in[16];
    float* out = (float*)d_out;

    char* ws = (char*)d_ws;
    float* h    = (float*)(ws);                        // 4 MB
    float* a_in = (float*)(ws + ((size_t)4 << 20));    // 4 MB
    float* a_out= (float*)(ws + ((size_t)8 << 20));    // 4 MB (12 MB total)

    for (int s = 0; s < NSTEPS; s++) {
        const float* hsrc = (s == 0) ? x : h;
        k_es<<<dim3(8, 64, 2), 256, 0, stream>>>(m, hsrc, W_in, b_in,
                                                 W_out, b_out, a_in, a_out,
                                                 s & 1);
        k_gate<<<4096, 256, 0, stream>>>(a_in, a_out, hsrc, h,
                                         Wz, bz, Wr, br, Wt, bt);
    }
    k_final<<<4096, 256, 0, stream>>>(h, a, W1, b1, W2, b2, out);
}